// Round 1
// baseline (130.906 us; speedup 1.0000x reference)
//
#include <hip/hip_runtime.h>

// Problem constants (match reference setup_inputs).
constexpr int Bc = 4;
constexpr int Nc = 2048;
constexpr int Dc = 3;
constexpr int Sc = 8;

// y[b,s,i,j] = exp(-(sum_d |x[b,i,d]-x[b,j,d]|)^2 / (2*sigma_s^2))
// One thread -> one (b,i) row, 4 consecutive j, all 8 sigmas.
__global__ __launch_bounds__(256) void gauss_l1_kernel(
    const float* __restrict__ x,       // [B, N, D=3]
    const float* __restrict__ sigmas,  // [S=8]
    float* __restrict__ out)           // [B, S, N, N]
{
    const int b = blockIdx.z;
    const int i = blockIdx.y;
    const int j0 = (blockIdx.x * blockDim.x + threadIdx.x) * 4;
    if (j0 >= Nc) return;

    // x[b,i,:] — uniform across the block (scalar loads).
    const float* xi = x + ((size_t)b * Nc + i) * Dc;
    const float xi0 = xi[0], xi1 = xi[1], xi2 = xi[2];

    // x[b,j0..j0+3,:] — 12 consecutive floats, 48B-aligned (j0 % 4 == 0 -> offset % 48 floats... bytes ok).
    const float4* xj4 = reinterpret_cast<const float4*>(x + ((size_t)b * Nc + j0) * Dc);
    const float4 p0 = xj4[0];  // j0:{x,y,z}, j1:{x}
    const float4 p1 = xj4[1];  // j1:{y,z},   j2:{x,y}
    const float4 p2 = xj4[2];  // j2:{z},     j3:{x,y,z}

    float d2[4];
    {
        float d;
        d = fabsf(xi0 - p0.x) + fabsf(xi1 - p0.y) + fabsf(xi2 - p0.z); d2[0] = d * d;
        d = fabsf(xi0 - p0.w) + fabsf(xi1 - p1.x) + fabsf(xi2 - p1.y); d2[1] = d * d;
        d = fabsf(xi0 - p1.z) + fabsf(xi1 - p1.w) + fabsf(xi2 - p2.x); d2[2] = d * d;
        d = fabsf(xi0 - p2.y) + fabsf(xi1 - p2.z) + fabsf(xi2 - p2.w); d2[3] = d * d;
    }

    // Precompute -1/(2*sigma^2) (uniform scalar loads; tiny).
    float inv[Sc];
    #pragma unroll
    for (int s = 0; s < Sc; ++s) {
        const float sg = sigmas[s];
        inv[s] = -1.0f / (2.0f * sg * sg);
    }

    const size_t row = ((size_t)b * Sc * Nc + i) * Nc + j0;  // offset for s=0
    #pragma unroll
    for (int s = 0; s < Sc; ++s) {
        float4 v;
        v.x = __expf(d2[0] * inv[s]);
        v.y = __expf(d2[1] * inv[s]);
        v.z = __expf(d2[2] * inv[s]);
        v.w = __expf(d2[3] * inv[s]);
        *reinterpret_cast<float4*>(out + row + (size_t)s * Nc * Nc) = v;
    }
}

extern "C" void kernel_launch(void* const* d_in, const int* in_sizes, int n_in,
                              void* d_out, int out_size, void* d_ws, size_t ws_size,
                              hipStream_t stream) {
    const float* x = (const float*)d_in[0];        // [B, N, 3] fp32
    const float* sigmas = (const float*)d_in[1];   // [8] fp32
    float* out = (float*)d_out;                    // [B, S, N, N] fp32

    dim3 block(256, 1, 1);
    dim3 grid(Nc / (256 * 4), Nc, Bc);             // (2, 2048, 4)
    gauss_l1_kernel<<<grid, block, 0, stream>>>(x, sigmas, out);
}